// Round 3
// baseline (103.909 us; speedup 1.0000x reference)
//
#include <hip/hip_runtime.h>

// Problem: B=2, T=2048, C=1024, H=16, D=64
// qkv = x @ w + b ; q,k,v split; att = relu(causal(q k^T / 8)); y = att @ v
// Output fp32 [B,T,C]. Compute in bf16 MFMA with fp32 accum.

typedef unsigned int u32;
typedef float  f32x4 __attribute__((ext_vector_type(4)));
typedef short  s16x8 __attribute__((ext_vector_type(8)));
typedef short  s16x4 __attribute__((ext_vector_type(4)));

#define MFMA_BF16(a, b, c) __builtin_amdgcn_mfma_f32_16x16x32_bf16((a), (b), (c), 0, 0, 0)
#define LO4(v) __builtin_shufflevector((v), (v), 0, 1, 2, 3)
#define HI4(v) __builtin_shufflevector((v), (v), 4, 5, 6, 7)

static __device__ __forceinline__ f32x4 mfma16(s16x4 a, s16x4 b, f32x4 c) {
#if __has_builtin(__builtin_amdgcn_mfma_f32_16x16x16bf16_1k)
  return __builtin_amdgcn_mfma_f32_16x16x16bf16_1k(a, b, c, 0, 0, 0);
#else
  f32x4 d;
  asm volatile("v_mfma_f32_16x16x16_bf16 %0, %1, %2, %3"
               : "=v"(d) : "v"(a), "v"(b), "v"(c));
  return d;
#endif
}

#define GLOAD16(g, l)                                                        \
  __builtin_amdgcn_global_load_lds(                                          \
      (__attribute__((address_space(1))) void*)(g),                          \
      (__attribute__((address_space(3))) void*)(l), 16, 0, 0)

__device__ __forceinline__ unsigned short f2bf(float f) {
  union { float f; u32 u; } x; x.f = f;
  u32 r = (x.u + 0x7fffu + ((x.u >> 16) & 1u)) >> 16;
  return (unsigned short)r;
}

// ---------------- kernel 1: x fp32 -> bf16 ----------------
__global__ void cvt_x_kernel(const float* __restrict__ x, unsigned short* __restrict__ xb) {
  int i = blockIdx.x * 256 + threadIdx.x;
  float4 v = ((const float4*)x)[i];
  ushort4 o;
  o.x = f2bf(v.x); o.y = f2bf(v.y); o.z = f2bf(v.z); o.w = f2bf(v.w);
  ((ushort4*)xb)[i] = o;
}

// ---------------- kernel 2: w [1024][3072] fp32 -> wT [3072][1024] bf16 ----
__global__ void transpose_w_kernel(const float* __restrict__ w, unsigned short* __restrict__ wT) {
  __shared__ unsigned short TL[64][72];
  const int tid = threadIdx.x;
  const int c0 = blockIdx.x * 64;
  const int r0 = blockIdx.y * 64;
#pragma unroll
  for (int p = 0; p < 4; ++p) {
    int r = p * 16 + (tid >> 4);
    int c = (tid & 15) * 4;
    float4 v = *(const float4*)&w[(size_t)(r0 + r) * 3072 + c0 + c];
    TL[c + 0][r] = f2bf(v.x);
    TL[c + 1][r] = f2bf(v.y);
    TL[c + 2][r] = f2bf(v.z);
    TL[c + 3][r] = f2bf(v.w);
  }
  __syncthreads();
#pragma unroll
  for (int p = 0; p < 4; ++p) {
    int c = p * 16 + (tid >> 4);
    int r = (tid & 15) * 4;
    ushort4 o;
    o.x = TL[c][r + 0]; o.y = TL[c][r + 1]; o.z = TL[c][r + 2]; o.w = TL[c][r + 3];
    *(ushort4*)&wT[(size_t)(c0 + c) * 1024 + r0 + r] = o;
  }
}

// ---------------- kernel 3: GEMM qkv = xb @ wT^T + bias  (bf16 out) -------
// q columns (bn < 8) are pre-scaled by 1/8 for the attention.
__global__ __launch_bounds__(256, 2) void gemm_qkv_kernel(
    const unsigned short* __restrict__ A, const unsigned short* __restrict__ Bt,
    const float* __restrict__ bias, unsigned short* __restrict__ Cq) {
  __shared__ __align__(16) unsigned short As[128 * 32];
  __shared__ __align__(16) unsigned short Bs[128 * 32];
  const int tid = threadIdx.x;
  const int lane = tid & 63, wid = tid >> 6;
  const int wr = wid >> 1, wc = wid & 1;
  const int g = lane >> 4, lm = lane & 15;
  const int bm = blockIdx.y, bn = blockIdx.x;

  const unsigned short* gA = A  + (size_t)(bm * 128 + wid * 32 + (lane >> 2)) * 1024 + (lane & 3) * 8;
  const unsigned short* gB = Bt + (size_t)(bn * 128 + wid * 32 + (lane >> 2)) * 1024 + (lane & 3) * 8;
  unsigned short* lA0 = &As[wid * 1024];
  unsigned short* lA1 = &As[wid * 1024 + 512];
  unsigned short* lB0 = &Bs[wid * 1024];
  unsigned short* lB1 = &Bs[wid * 1024 + 512];

  f32x4 acc[4][4] = {};

  for (int kt = 0; kt < 32; ++kt) {
    __syncthreads();
    const unsigned short* a0 = gA + kt * 32;
    const unsigned short* b0 = gB + kt * 32;
    GLOAD16(a0,             lA0);
    GLOAD16(a0 + 16 * 1024, lA1);
    GLOAD16(b0,             lB0);
    GLOAD16(b0 + 16 * 1024, lB1);
    __syncthreads();

    s16x8 af[4], bf[4];
#pragma unroll
    for (int m = 0; m < 4; ++m)
      af[m] = *(const s16x8*)&As[(wr * 64 + m * 16 + lm) * 32 + g * 8];
#pragma unroll
    for (int n = 0; n < 4; ++n)
      bf[n] = *(const s16x8*)&Bs[(wc * 64 + n * 16 + lm) * 32 + g * 8];
#pragma unroll
    for (int m = 0; m < 4; ++m)
#pragma unroll
      for (int n = 0; n < 4; ++n)
        acc[m][n] = MFMA_BF16(af[m], bf[n], acc[m][n]);
  }

  const float qs = (bn < 8) ? 0.125f : 1.0f;   // fold attention scale into q
#pragma unroll
  for (int m = 0; m < 4; ++m) {
    const int row = bm * 128 + wr * 64 + m * 16 + g * 4;
#pragma unroll
    for (int n = 0; n < 4; ++n) {
      const int col = bn * 128 + wc * 64 + n * 16 + lm;
      const float bv = bias[col];
#pragma unroll
      for (int r = 0; r < 4; ++r)
        Cq[(size_t)(row + r) * 3072 + col] = f2bf((acc[m][n][r] + bv) * qs);
    }
  }
}

// ---------------- kernel 4: V part of qkv -> Vt [B][H][D][T] bf16 ---------
__global__ void transpose_v_kernel(const unsigned short* __restrict__ qkv,
                                   unsigned short* __restrict__ Vt) {
  __shared__ unsigned short TL[64][72];
  const int tid = threadIdx.x;
  const int t0 = blockIdx.x * 64;
  const int h = blockIdx.y;
  const int b = blockIdx.z;
#pragma unroll
  for (int p = 0; p < 2; ++p) {
    int t = p * 32 + (tid >> 3), dc = tid & 7;
    s16x8 v = *(const s16x8*)&qkv[(size_t)(b * 2048 + t0 + t) * 3072 + 2048 + h * 64 + dc * 8];
#pragma unroll
    for (int j = 0; j < 8; ++j) TL[dc * 8 + j][t] = (unsigned short)v[j];
  }
  __syncthreads();
#pragma unroll
  for (int p = 0; p < 2; ++p) {
    int d = p * 32 + (tid >> 3), tc = tid & 7;
    s16x8 o = *(const s16x8*)&TL[d][tc * 8];
    *(s16x8*)&Vt[((size_t)((b * 16 + h) * 64 + d)) * 2048 + t0 + tc * 8] = o;
  }
}

// ---------------- kernel 5: attention v3 ----------------------------------
// Work-queue: per (b,h), 272 KV-step units over 16 q-tiles of 128 rows
// (tile qb has 2qb+2 units); 16 blocks x exactly 17 units. 8 waves/block,
// wave owns 16 q rows. P stays in registers (16x16x16 PV). Partial tiles
// flushed with atomicAdd (out pre-zeroed).
__global__ __launch_bounds__(512, 4) void attn_kernel(
    const unsigned short* __restrict__ qkv, const unsigned short* __restrict__ Vt,
    float* __restrict__ out) {
  __shared__ __align__(16) unsigned short Ks[2][64 * 64];   // [s][d] swizzled
  __shared__ __align__(16) unsigned short Vs[2][64 * 64];   // [d][s''] swizzled
  const int tid = threadIdx.x, lane = tid & 63, wid = tid >> 6;  // wid 0..7
  const int g = lane >> 4, lm = lane & 15;
  const int kq = blockIdx.x;                 // 0..15 queue block
  const int h = blockIdx.y, b = blockIdx.z;
  const size_t qbase = (size_t)(b * 2048) * 3072 + h * 64;
  const size_t kbase = qbase + 1024;
  const size_t vbase = (size_t)((b * 16 + h) * 64) * 2048;

  // staging: 512 threads, thread -> row sr, 8-elem chunk sj
  const int sr = tid >> 3;                   // 0..63 (K: s row, V: d row)
  const int sj = tid & 7;
  const int swzw = (sr & 7) << 3;
  const unsigned kw = sr * 64 + ((sj * 8) ^ swzw);
  // V s-regroup: s = 16c + 4g + r  ->  s'' = 16g + 4c + r
  const int gA = (2 * sj) & 3, gB = (2 * sj + 1) & 3, cc = sj >> 1;
  const unsigned vwA = sr * 64 + ((gA * 16 + cc * 4) ^ swzw);
  const unsigned vwB = sr * 64 + ((gB * 16 + cc * 4) ^ swzw);

  const int msk = (lm & 7) << 3;

  // locate start unit: tri(qb) = qb*(qb+1)
  const int u0 = kq * 17;
  int qb = 0;
  while ((qb + 1) * (qb + 2) <= u0) ++qb;
  int st = u0 - qb * (qb + 1);

  int qrow = qb * 128 + wid * 16;
  s16x8 qf0 = *(const s16x8*)&qkv[qbase + (size_t)(qrow + lm) * 3072 + g * 8];
  s16x8 qf1 = *(const s16x8*)&qkv[qbase + (size_t)(qrow + lm) * 3072 + 32 + g * 8];
  f32x4 yacc[4] = {};

  // stage first unit
  s16x8 kr = *(const s16x8*)&qkv[kbase + (size_t)(st * 64 + sr) * 3072 + sj * 8];
  s16x8 vr = *(const s16x8*)&Vt[vbase + (size_t)sr * 2048 + st * 64 + sj * 8];
  *(s16x8*)&Ks[0][kw] = kr;
  *(s16x4*)&Vs[0][vwA] = LO4(vr);
  *(s16x4*)&Vs[0][vwB] = HI4(vr);
  __syncthreads();

  int cur = 0;
  for (int i = 0; i < 17; ++i) {
    int qb2 = qb, st2 = st + 1;
    if (st2 == 2 * qb + 2) { qb2 = qb + 1; st2 = 0; }
    const bool pf = (i < 16);
    if (pf) {
      kr = *(const s16x8*)&qkv[kbase + (size_t)(st2 * 64 + sr) * 3072 + sj * 8];
      vr = *(const s16x8*)&Vt[vbase + (size_t)sr * 2048 + st2 * 64 + sj * 8];
    }
    const int s0 = st * 64;
    const bool diag = (st >= 2 * qb);
    const unsigned short* Kc = Ks[cur];
    const unsigned short* Vc = Vs[cur];

    s16x4 pfr[4];
#pragma unroll
    for (int sb = 0; sb < 4; ++sb) {
      s16x8 kf0 = *(const s16x8*)&Kc[(sb * 16 + lm) * 64 + ((g * 8) ^ msk)];
      s16x8 kf1 = *(const s16x8*)&Kc[(sb * 16 + lm) * 64 + ((32 + g * 8) ^ msk)];
      f32x4 z = {};
      f32x4 sacc = MFMA_BF16(kf1, qf1, z);        // S^T: rows=s, cols=q
      sacc = MFMA_BF16(kf0, qf0, sacc);
      const int sg = s0 + sb * 16 + g * 4;
      const int qg = qrow + lm;
      s16x4 p;
#pragma unroll
      for (int r2 = 0; r2 < 4; ++r2) {
        float v = sacc[r2];
        v = v > 0.0f ? v : 0.0f;
        if (diag && (sg + r2 > qg)) v = 0.0f;
        p[r2] = (short)f2bf(v);
      }
      pfr[sb] = p;
    }

#pragma unroll
    for (int db = 0; db < 4; ++db) {
      const unsigned base = (unsigned)(db * 16 + lm) * 64;
      s16x8 va = *(const s16x8*)&Vc[base + ((g * 16) ^ msk)];      // chunks 0,1
      s16x8 vb = *(const s16x8*)&Vc[base + ((g * 16 + 8) ^ msk)];  // chunks 2,3
      yacc[db] = mfma16(pfr[0], LO4(va), yacc[db]);
      yacc[db] = mfma16(pfr[1], HI4(va), yacc[db]);
      yacc[db] = mfma16(pfr[2], LO4(vb), yacc[db]);
      yacc[db] = mfma16(pfr[3], HI4(vb), yacc[db]);
    }

    if (pf) {
      *(s16x8*)&Ks[cur ^ 1][kw] = kr;
      *(s16x4*)&Vs[cur ^ 1][vwA] = LO4(vr);
      *(s16x4*)&Vs[cur ^ 1][vwB] = HI4(vr);
    }

    if (qb2 != qb || i == 16) {                    // flush partial tile
      const size_t obase = (size_t)(b * 2048 + qrow) * 1024 + h * 64;
#pragma unroll
      for (int db = 0; db < 4; ++db)
#pragma unroll
        for (int r2 = 0; r2 < 4; ++r2)
          atomicAdd(&out[obase + (size_t)(g * 4 + r2) * 1024 + db * 16 + lm],
                    yacc[db][r2]);
      if (qb2 != qb && i < 16) {
        qrow = qb2 * 128 + wid * 16;
        qf0 = *(const s16x8*)&qkv[qbase + (size_t)(qrow + lm) * 3072 + g * 8];
        qf1 = *(const s16x8*)&qkv[qbase + (size_t)(qrow + lm) * 3072 + 32 + g * 8];
#pragma unroll
        for (int db = 0; db < 4; ++db) yacc[db] = (f32x4){0.f, 0.f, 0.f, 0.f};
      }
    }
    __syncthreads();
    cur ^= 1; qb = qb2; st = st2;
  }
}

extern "C" void kernel_launch(void* const* d_in, const int* in_sizes, int n_in,
                              void* d_out, int out_size, void* d_ws, size_t ws_size,
                              hipStream_t stream) {
  const float* x    = (const float*)d_in[0];
  const float* w    = (const float*)d_in[1];
  const float* bias = (const float*)d_in[2];
  float* out = (float*)d_out;

  unsigned short* xb  = (unsigned short*)d_ws;            // 4096*1024
  unsigned short* wT  = xb + (size_t)4096 * 1024;         // 3072*1024
  unsigned short* qkv = wT + (size_t)3072 * 1024;         // 4096*3072
  unsigned short* Vt  = xb;                               // reuse (xb dead after GEMM)

  hipMemsetAsync(d_out, 0, (size_t)out_size * sizeof(float), stream);
  cvt_x_kernel<<<4096, 256, 0, stream>>>(x, xb);
  transpose_w_kernel<<<dim3(48, 16), 256, 0, stream>>>(w, wT);
  gemm_qkv_kernel<<<dim3(24, 32), 256, 0, stream>>>(xb, wT, bias, qkv);
  transpose_v_kernel<<<dim3(32, 16, 2), 256, 0, stream>>>(qkv, Vt);
  attn_kernel<<<dim3(16, 16, 2), 512, 0, stream>>>(qkv, Vt, out);
}

// Round 4
// 94.346 us; speedup vs baseline: 1.1014x; 1.1014x over previous
//
#include <hip/hip_runtime.h>

// Problem: B=2, T=2048, C=1024, H=16, D=64
// qkv = x @ w + b ; q,k,v split; att = relu(causal(q k^T / 8)); y = att @ v
// Output fp32 [B,T,C]. Compute in bf16 MFMA with fp32 accum.

typedef unsigned int u32;
typedef float  f32x4 __attribute__((ext_vector_type(4)));
typedef short  s16x8 __attribute__((ext_vector_type(8)));
typedef short  s16x4 __attribute__((ext_vector_type(4)));

#define MFMA_BF16(a, b, c) __builtin_amdgcn_mfma_f32_16x16x32_bf16((a), (b), (c), 0, 0, 0)

static __device__ __forceinline__ f32x4 mfma16(s16x4 a, s16x4 b, f32x4 c) {
#if __has_builtin(__builtin_amdgcn_mfma_f32_16x16x16bf16_1k)
  return __builtin_amdgcn_mfma_f32_16x16x16bf16_1k(a, b, c, 0, 0, 0);
#else
  f32x4 d;
  asm volatile("v_mfma_f32_16x16x16_bf16 %0, %1, %2, %3"
               : "=&v"(d) : "v"(a), "v"(b), "v"(c));
  return d;
#endif
}

// pack 4 floats -> 4 bf16 via HW round-to-nearest-even
static __device__ __forceinline__ s16x4 cvtpk4(float a, float b, float c, float d) {
  union { s16x4 v; u32 w[2]; } r;
  asm("v_cvt_pk_bf16_f32 %0, %1, %2" : "=v"(r.w[0]) : "v"(a), "v"(b));
  asm("v_cvt_pk_bf16_f32 %0, %1, %2" : "=v"(r.w[1]) : "v"(c), "v"(d));
  return r.v;
}

#define GLOAD16(g, l)                                                        \
  __builtin_amdgcn_global_load_lds(                                          \
      (__attribute__((address_space(1))) void*)(g),                          \
      (__attribute__((address_space(3))) void*)(l), 16, 0, 0)

__device__ __forceinline__ unsigned short f2bf(float f) {
  union { float f; u32 u; } x; x.f = f;
  u32 r = (x.u + 0x7fffu + ((x.u >> 16) & 1u)) >> 16;
  return (unsigned short)r;
}

// ---------------- kernel 1: x fp32 -> bf16 ----------------
__global__ void cvt_x_kernel(const float* __restrict__ x, unsigned short* __restrict__ xb) {
  int i = blockIdx.x * 256 + threadIdx.x;
  float4 v = ((const float4*)x)[i];
  ushort4 o;
  o.x = f2bf(v.x); o.y = f2bf(v.y); o.z = f2bf(v.z); o.w = f2bf(v.w);
  ((ushort4*)xb)[i] = o;
}

// ---------------- kernel 2: w [1024][3072] fp32 -> wT [3072][1024] bf16 ----
__global__ void transpose_w_kernel(const float* __restrict__ w, unsigned short* __restrict__ wT) {
  __shared__ unsigned short TL[64][72];
  const int tid = threadIdx.x;
  const int c0 = blockIdx.x * 64;
  const int r0 = blockIdx.y * 64;
#pragma unroll
  for (int p = 0; p < 4; ++p) {
    int r = p * 16 + (tid >> 4);
    int c = (tid & 15) * 4;
    float4 v = *(const float4*)&w[(size_t)(r0 + r) * 3072 + c0 + c];
    TL[c + 0][r] = f2bf(v.x);
    TL[c + 1][r] = f2bf(v.y);
    TL[c + 2][r] = f2bf(v.z);
    TL[c + 3][r] = f2bf(v.w);
  }
  __syncthreads();
#pragma unroll
  for (int p = 0; p < 4; ++p) {
    int c = p * 16 + (tid >> 4);
    int r = (tid & 15) * 4;
    ushort4 o;
    o.x = TL[c][r + 0]; o.y = TL[c][r + 1]; o.z = TL[c][r + 2]; o.w = TL[c][r + 3];
    *(ushort4*)&wT[(size_t)(c0 + c) * 1024 + r0 + r] = o;
  }
}

// ---------------- kernel 3: GEMM qkv = xb @ wT^T + bias ------------------
// bn<8: q (pre-scaled 1/8) -> Cq[.][0:1024); bn in [8,16): k -> Cq[.][1024:2048)
// bn>=16: v written TRANSPOSED to Vt [B][H][D][T] (ushort4, t-contiguous).
__global__ __launch_bounds__(256, 2) void gemm_qkv_kernel(
    const unsigned short* __restrict__ A, const unsigned short* __restrict__ Bt,
    const float* __restrict__ bias, unsigned short* __restrict__ Cq,
    unsigned short* __restrict__ Vt) {
  __shared__ __align__(16) unsigned short As[128 * 32];
  __shared__ __align__(16) unsigned short Bs[128 * 32];
  const int tid = threadIdx.x;
  const int lane = tid & 63, wid = tid >> 6;
  const int wr = wid >> 1, wc = wid & 1;
  const int g = lane >> 4, lm = lane & 15;
  const int bm = blockIdx.y, bn = blockIdx.x;

  const unsigned short* gA = A  + (size_t)(bm * 128 + wid * 32 + (lane >> 2)) * 1024 + (lane & 3) * 8;
  const unsigned short* gB = Bt + (size_t)(bn * 128 + wid * 32 + (lane >> 2)) * 1024 + (lane & 3) * 8;
  unsigned short* lA0 = &As[wid * 1024];
  unsigned short* lA1 = &As[wid * 1024 + 512];
  unsigned short* lB0 = &Bs[wid * 1024];
  unsigned short* lB1 = &Bs[wid * 1024 + 512];

  f32x4 acc[4][4] = {};

  for (int kt = 0; kt < 32; ++kt) {
    __syncthreads();
    const unsigned short* a0 = gA + kt * 32;
    const unsigned short* b0 = gB + kt * 32;
    GLOAD16(a0,             lA0);
    GLOAD16(a0 + 16 * 1024, lA1);
    GLOAD16(b0,             lB0);
    GLOAD16(b0 + 16 * 1024, lB1);
    __syncthreads();

    s16x8 af[4], bf[4];
#pragma unroll
    for (int m = 0; m < 4; ++m)
      af[m] = *(const s16x8*)&As[(wr * 64 + m * 16 + lm) * 32 + g * 8];
#pragma unroll
    for (int n = 0; n < 4; ++n)
      bf[n] = *(const s16x8*)&Bs[(wc * 64 + n * 16 + lm) * 32 + g * 8];
#pragma unroll
    for (int m = 0; m < 4; ++m)
#pragma unroll
      for (int n = 0; n < 4; ++n)
        acc[m][n] = MFMA_BF16(af[m], bf[n], acc[m][n]);
  }

  if (bn < 16) {
    const float qs = (bn < 8) ? 0.125f : 1.0f;   // fold attention scale into q
#pragma unroll
    for (int m = 0; m < 4; ++m) {
      const int row = bm * 128 + wr * 64 + m * 16 + g * 4;
#pragma unroll
      for (int n = 0; n < 4; ++n) {
        const int col = bn * 128 + wc * 64 + n * 16 + lm;
        const float bv = bias[col];
#pragma unroll
        for (int r = 0; r < 4; ++r)
          Cq[(size_t)(row + r) * 2048 + col] = f2bf((acc[m][n][r] + bv) * qs);
      }
    }
  } else {
#pragma unroll
    for (int m = 0; m < 4; ++m) {
      const int row = bm * 128 + wr * 64 + m * 16 + g * 4;   // b*2048 + t
      const int bb = row >> 11, tt = row & 2047;
#pragma unroll
      for (int n = 0; n < 4; ++n) {
        const int col = bn * 128 + wc * 64 + n * 16 + lm;
        const int cv = col - 2048;                           // h*64 + d
        const float bv = bias[col];
        ushort4 o;
#pragma unroll
        for (int r = 0; r < 4; ++r)
          ((unsigned short*)&o)[r] = f2bf(acc[m][n][r] + bv);
        *(ushort4*)&Vt[((size_t)(bb * 1024 + cv)) * 2048 + tt] = o;
      }
    }
  }
}

// ---------------- kernel 4: attention v4 ----------------------------------
// Work-queue: per (b,h), 272 KV-step units over 16 q-tiles of 128 rows;
// 16 blocks x 17 units. 8 waves, 16 q rows/wave. P in registers via
// HW cvt_pk; V tile stored plain [d][s] (K-style swizzle), PV = 16x16x16
// with b64 B-reads. Partial tiles flushed with atomicAdd (out pre-zeroed).
__global__ __launch_bounds__(512, 2) void attn_kernel(
    const unsigned short* __restrict__ qkv, const unsigned short* __restrict__ Vt,
    float* __restrict__ out) {
  __shared__ __align__(16) unsigned short Ks[2][64 * 64];   // [s][d] swizzled
  __shared__ __align__(16) unsigned short Vs[2][64 * 64];   // [d][s] swizzled
  const int tid = threadIdx.x, lane = tid & 63, wid = tid >> 6;  // wid 0..7
  const int g = lane >> 4, lm = lane & 15;
  const int kq = blockIdx.x;                 // 0..15 queue block
  const int h = blockIdx.y, b = blockIdx.z;
  const size_t qbase = (size_t)(b * 2048) * 2048 + h * 64;
  const size_t kbase = qbase + 1024;
  const size_t vtbase = (size_t)(b * 1024 + h * 64) * 2048;

  // staging: 512 threads, thread -> row sr (K: s, V: d), 8-elem chunk sj
  const int sr = tid >> 3;                   // 0..63
  const int sj = tid & 7;
  const unsigned lw = sr * 64 + ((sj * 8) ^ ((sr & 7) << 3));
  const int msk = (lm & 7) << 3;             // read-side swizzle

  // locate start unit: tri(qb) = qb*(qb+1)
  const int u0 = kq * 17;
  int qb = 0;
  while ((qb + 1) * (qb + 2) <= u0) ++qb;
  int st = u0 - qb * (qb + 1);

  int qrow = qb * 128 + wid * 16;
  s16x8 qf0 = *(const s16x8*)&qkv[qbase + (size_t)(qrow + lm) * 2048 + g * 8];
  s16x8 qf1 = *(const s16x8*)&qkv[qbase + (size_t)(qrow + lm) * 2048 + 32 + g * 8];
  f32x4 yacc[4] = {};

  // stage first unit
  s16x8 kr = *(const s16x8*)&qkv[kbase + (size_t)(st * 64 + sr) * 2048 + sj * 8];
  s16x8 vr = *(const s16x8*)&Vt[vtbase + (size_t)sr * 2048 + st * 64 + sj * 8];
  *(s16x8*)&Ks[0][lw] = kr;
  *(s16x8*)&Vs[0][lw] = vr;
  __syncthreads();

  int cur = 0;
  for (int i = 0; i < 17; ++i) {
    int qb2 = qb, st2 = st + 1;
    if (st2 == 2 * qb + 2) { qb2 = qb + 1; st2 = 0; }
    const bool pf = (i < 16);
    if (pf) {
      kr = *(const s16x8*)&qkv[kbase + (size_t)(st2 * 64 + sr) * 2048 + sj * 8];
      vr = *(const s16x8*)&Vt[vtbase + (size_t)sr * 2048 + st2 * 64 + sj * 8];
    }
    const int s0 = st * 64;
    const bool diag = (st >= 2 * qb);
    const unsigned short* Kc = Ks[cur];
    const unsigned short* Vc = Vs[cur];

    s16x4 pfr[4];
#pragma unroll
    for (int sb = 0; sb < 4; ++sb) {
      s16x8 kf0 = *(const s16x8*)&Kc[(sb * 16 + lm) * 64 + ((g * 8) ^ msk)];
      s16x8 kf1 = *(const s16x8*)&Kc[(sb * 16 + lm) * 64 + ((32 + g * 8) ^ msk)];
      f32x4 z = {};
      f32x4 sacc = MFMA_BF16(kf1, qf1, z);        // S^T: rows=s, cols=q
      sacc = MFMA_BF16(kf0, qf0, sacc);
      float p0 = sacc[0] > 0.f ? sacc[0] : 0.f;
      float p1 = sacc[1] > 0.f ? sacc[1] : 0.f;
      float p2 = sacc[2] > 0.f ? sacc[2] : 0.f;
      float p3 = sacc[3] > 0.f ? sacc[3] : 0.f;
      if (diag) {                                 // wave-uniform branch
        const int sg = s0 + sb * 16 + g * 4;
        const int qg = qrow + lm;
        if (sg + 0 > qg) p0 = 0.f;
        if (sg + 1 > qg) p1 = 0.f;
        if (sg + 2 > qg) p2 = 0.f;
        if (sg + 3 > qg) p3 = 0.f;
      }
      pfr[sb] = cvtpk4(p0, p1, p2, p3);
    }

    __builtin_amdgcn_s_setprio(1);
#pragma unroll
    for (int db = 0; db < 4; ++db) {
      const unsigned vrow = (unsigned)(db * 16 + lm) * 64;
#pragma unroll
      for (int c = 0; c < 4; ++c) {
        s16x4 vf = *(const s16x4*)&Vc[vrow + (unsigned)((c * 16 + g * 4) ^ msk)];
        yacc[db] = mfma16(pfr[c], vf, yacc[db]);
      }
    }
    __builtin_amdgcn_s_setprio(0);

    if (pf) {
      *(s16x8*)&Ks[cur ^ 1][lw] = kr;
      *(s16x8*)&Vs[cur ^ 1][lw] = vr;
    }

    if (qb2 != qb || i == 16) {                    // flush (partial) tile
      const size_t obase = (size_t)(b * 2048 + qrow) * 1024 + h * 64;
#pragma unroll
      for (int db = 0; db < 4; ++db)
#pragma unroll
        for (int r2 = 0; r2 < 4; ++r2)
          atomicAdd(&out[obase + (size_t)(g * 4 + r2) * 1024 + db * 16 + lm],
                    yacc[db][r2]);
      if (qb2 != qb && i < 16) {
        qrow = qb2 * 128 + wid * 16;
        qf0 = *(const s16x8*)&qkv[qbase + (size_t)(qrow + lm) * 2048 + g * 8];
        qf1 = *(const s16x8*)&qkv[qbase + (size_t)(qrow + lm) * 2048 + 32 + g * 8];
#pragma unroll
        for (int db = 0; db < 4; ++db) yacc[db] = (f32x4){0.f, 0.f, 0.f, 0.f};
      }
    }
    __syncthreads();
    cur ^= 1; qb = qb2; st = st2;
  }
}

extern "C" void kernel_launch(void* const* d_in, const int* in_sizes, int n_in,
                              void* d_out, int out_size, void* d_ws, size_t ws_size,
                              hipStream_t stream) {
  const float* x    = (const float*)d_in[0];
  const float* w    = (const float*)d_in[1];
  const float* bias = (const float*)d_in[2];
  float* out = (float*)d_out;

  unsigned short* xb  = (unsigned short*)d_ws;            // 4096*1024 elems
  unsigned short* wT  = xb  + (size_t)4096 * 1024;        // 3072*1024
  unsigned short* qkv = wT  + (size_t)3072 * 1024;        // 4096*2048 (q|k)
  unsigned short* Vt  = qkv + (size_t)4096 * 2048;        // 1024*2048*2 (v^T)

  hipMemsetAsync(d_out, 0, (size_t)out_size * sizeof(float), stream);
  cvt_x_kernel<<<4096, 256, 0, stream>>>(x, xb);
  transpose_w_kernel<<<dim3(48, 16), 256, 0, stream>>>(w, wT);
  gemm_qkv_kernel<<<dim3(24, 32), 256, 0, stream>>>(xb, wT, bias, qkv, Vt);
  attn_kernel<<<dim3(16, 16, 2), 512, 0, stream>>>(qkv, Vt, out);
}